// Round 3
// baseline (110.209 us; speedup 1.0000x reference)
//
#include <hip/hip_runtime.h>

// VQ nearest-neighbor via f16-split MFMA. N=65536 queries, DIM=64, K=1024.
// v = dot(z,c) - csq[k]/2; argmax_k v  ==  argmin_k ||z-c||^2.
// 2-term f16 split (absmax=0 verified): dot ~= zh.ch + 2^-11(zh.cl'+zl'.ch).
//
// Round-8: fix round 7's spill (VGPR_Count=64 -> accvgpr shuttle + scratch,
// VALU 3x model, vq 50us). Keep 4 waves/SIMD (cap = 512/4 = 128 regs) but
// make the kernel honestly fit:
//  * csq folded into the codebook stream: each 4352-B tile = [64 f32
//    lane-broadcast -csq/2][kt0h][kt0l][kt1h][kt1l]. No LDS csqn, no
//    pre-loop barrier, no ds_read in the loop: c loads on the same vmcnt
//    path at an imm offset.
//  * Wave-uniform tile base -> SGPR bump (SALU); per-lane byte offsets
//    (lane*4, lane*16) are loop-invariant; frag selects are imm offsets
//    (256/1280/2304/3328, all <= 4095).
//  * bestt stays byte-packed (4 regs vs 16); update is the bfi pattern
//    (mask compile-time, t*0x01010101 wave-uniform): 5 VALU/slot.
//  * No setprio (wrong regime; its regions extend live ranges).
// Budget: A 64 + B 16 + best 16 + bestt 4 + acc 8 + offs ~6 ~= 114 < 128.

typedef _Float16 half8 __attribute__((ext_vector_type(8)));
typedef float float4v __attribute__((ext_vector_type(4)));

constexpr int KCODES = 1024;
constexpr int DIM = 64;
constexpr int BLOCK = 256;

// Tile layout in d_ws (64 tiles of 16 codes each):
//   byte 0..255   : 64 f32, slot (quad*16+m) = -csq[T*16+m]/2 (lane-bcast)
//   byte 256+     : 4 frags x 512 halfs: kt0h, kt0l, kt1h, kt1l
//   frag halfs    : [(quad*16+m)*8 + j], dim = kt*32 + quad*8 + j
constexpr int TILE_BYTES = 4352;

__global__ __launch_bounds__(BLOCK) void prep_kernel(
    const float* __restrict__ cb, char* __restrict__ cbf) {
  const int g = blockIdx.x * BLOCK + threadIdx.x;  // grid 32 x 256 = 8192
  const int k = g >> 3, sub = g & 7;
  const int kt = sub >> 2, quad = sub & 3;
  const int T = k >> 4, m = k & 15;

  const float* src = cb + (size_t)k * DIM + kt * 32 + quad * 8;
  const float4 p0 = ((const float4*)src)[0];
  const float4 p1 = ((const float4*)src)[1];
  const float x[8] = {p0.x, p0.y, p0.z, p0.w, p1.x, p1.y, p1.z, p1.w};

  half8 h8, l8;
  float s = 0.f;
#pragma unroll
  for (int j = 0; j < 8; ++j) {
    s = fmaf(x[j], x[j], s);
    const _Float16 h = (_Float16)x[j];
    h8[j] = h;
    l8[j] = (_Float16)((x[j] - (float)h) * 2048.0f);
  }
  // csq summed over the 8 sub-threads of this code (xor 1/2/4 stays in-wave).
  s += __shfl_xor(s, 1);
  s += __shfl_xor(s, 2);
  s += __shfl_xor(s, 4);

  char* tbase = cbf + (size_t)T * TILE_BYTES;
  if (kt == 0) ((float*)tbase)[quad * 16 + m] = -0.5f * s;  // 4 bcast copies

  _Float16* dst =
      (_Float16*)(tbase + 256) + (size_t)(kt * 2) * 512 + (quad * 16 + m) * 8;
  *(half8*)(dst) = h8;        // hl = 0
  *(half8*)(dst + 512) = l8;  // hl = 1
}

// Block = 256 thr = 4 waves = 1 query-group (64 q) x 4 K-quarters.
__global__ __launch_bounds__(BLOCK, 4) void vq_mfma(
    const float* __restrict__ z, const float4* __restrict__ cb4,
    const char* __restrict__ cbf, float4* __restrict__ out4) {
  __shared__ float rv[4][64];
  __shared__ int rk[4][64];
  __shared__ int sidx[64];

  const int tid = threadIdx.x;
  const int lane = tid & 63;
  const int kh = tid >> 6;    // wave = K quarter (16 tiles = 256 codes)
  const int m = lane & 15;
  const int quad = lane >> 4;

  // A-fragments: 4 qtiles x 2 ktiles, h + l. A[m][k=quad*8+j].
  const int qbase = blockIdx.x * 64;
  half8 ah[4][2], al[4][2];
#pragma unroll
  for (int qt = 0; qt < 4; ++qt) {
    const float* zr = z + (size_t)(qbase + qt * 16 + m) * DIM + quad * 8;
#pragma unroll
    for (int kt = 0; kt < 2; ++kt) {
      const float4 p0 = ((const float4*)(zr + kt * 32))[0];
      const float4 p1 = ((const float4*)(zr + kt * 32))[1];
      const float zf[8] = {p0.x, p0.y, p0.z, p0.w, p1.x, p1.y, p1.z, p1.w};
#pragma unroll
      for (int j = 0; j < 8; ++j) {
        const _Float16 h = (_Float16)zf[j];
        ah[qt][kt][j] = h;
        al[qt][kt][j] = (_Float16)((zf[j] - (float)h) * 2048.0f);
      }
    }
  }

  const float4v zvec = {0.f, 0.f, 0.f, 0.f};
  float best[4][4];
  unsigned bestt[4];  // byte r of bestt[qt] = winning tile id for slot r
#pragma unroll
  for (int qt = 0; qt < 4; ++qt) {
    bestt[qt] = 0u;
#pragma unroll
    for (int r = 0; r < 4; ++r) best[qt][r] = -3.402823466e38f;
  }

  // Wave-uniform tile base (SGPR + SALU bump); per-lane offsets invariant.
  const char* tb = cbf + (size_t)(kh * 16) * TILE_BYTES;
  const int coff = lane * 4;         // c slot
  const int boff = 256 + lane * 16;  // frag base (imm +1024/+2048/+3072)

#pragma unroll 1
  for (int t = 0; t < 16; ++t, tb += TILE_BYTES) {
    const float c = *(const float*)(tb + coff);
    const _Float16* bp = (const _Float16*)(tb + boff);
    const half8 bh0 = *(const half8*)(bp);          // kt0, h
    const half8 bl0 = *(const half8*)(bp + 512);    // kt0, l
    const half8 bh1 = *(const half8*)(bp + 1024);   // kt1, h
    const half8 bl1 = *(const half8*)(bp + 1536);   // kt1, l

    const float4v cvec = {c, c, c, c};
    const unsigned tq = (unsigned)t * 0x01010101u;  // wave-uniform

#pragma unroll
    for (int qt = 0; qt < 4; ++qt) {
      float4v am = __builtin_amdgcn_mfma_f32_16x16x32_f16(ah[qt][0], bh0, cvec, 0, 0, 0);
      am = __builtin_amdgcn_mfma_f32_16x16x32_f16(ah[qt][1], bh1, am, 0, 0, 0);
      float4v ax = __builtin_amdgcn_mfma_f32_16x16x32_f16(ah[qt][0], bl0, zvec, 0, 0, 0);
      ax = __builtin_amdgcn_mfma_f32_16x16x32_f16(ah[qt][1], bl1, ax, 0, 0, 0);
      ax = __builtin_amdgcn_mfma_f32_16x16x32_f16(al[qt][0], bh0, ax, 0, 0, 0);
      ax = __builtin_amdgcn_mfma_f32_16x16x32_f16(al[qt][1], bh1, ax, 0, 0, 0);
#pragma unroll
      for (int r = 0; r < 4; ++r) {
        const float v = fmaf(4.8828125e-4f, ax[r], am[r]);  // 2^-11
        const unsigned mask = 0xFFu << (8 * r);             // compile-time
        const unsigned cand = (bestt[qt] & ~mask) | (tq & mask);  // bfi
        // k ascending in t per lane: strict > keeps lowest-k maximum.
        const bool gt = v > best[qt][r];
        best[qt][r] = gt ? v : best[qt][r];
        bestt[qt] = gt ? cand : bestt[qt];
      }
    }
  }

  // Cross-lane argmax over the 16 cols (m) in each quad; ties -> lower k.
  const int kbase = kh * 256 + m;
#pragma unroll
  for (int qt = 0; qt < 4; ++qt)
#pragma unroll
    for (int r = 0; r < 4; ++r) {
      float b = best[qt][r];
      int bk = kbase + (int)((bestt[qt] >> (8 * r)) & 0xFFu) * 16;
#pragma unroll
      for (int s = 1; s < 16; s <<= 1) {
        const float ob = __shfl_xor(b, s);
        const int obk = __shfl_xor(bk, s);
        if (ob > b || (ob == b && obk < bk)) { b = ob; bk = obk; }
      }
      if (m == 0) {
        const int qb = qt * 16 + quad * 4 + r;  // row = quad*4+r
        rv[kh][qb] = b;
        rk[kh][qb] = bk;
      }
    }
  __syncthreads();

  // Combine K-quarters (strict >: ties -> lower kh = lower k).
  if (tid < 64) {
    float v = rv[0][tid];
    int bk = rk[0][tid];
#pragma unroll
    for (int h = 1; h < 4; ++h) {
      const float vh = rv[h][tid];
      const int kh2 = rk[h][tid];
      if (vh > v) { v = vh; bk = kh2; }
    }
    sidx[tid] = bk;
  }
  __syncthreads();

  // Gather winning fp32 codebook rows; coalesced float4 writes.
  const size_t obase = (size_t)blockIdx.x * 64 * (DIM / 4);
#pragma unroll
  for (int f0 = 0; f0 < 64 * (DIM / 4); f0 += BLOCK) {
    const int f = f0 + tid;
    const int q = f >> 4, e = f & 15;
    out4[obase + f] = cb4[(size_t)sidx[q] * (DIM / 4) + e];
  }
}

extern "C" void kernel_launch(void* const* d_in, const int* in_sizes, int n_in,
                              void* d_out, int out_size, void* d_ws, size_t ws_size,
                              hipStream_t stream) {
  const float* z = (const float*)d_in[0];
  const float* cb = (const float*)d_in[1];
  char* cbf = (char*)d_ws;  // 64 tiles x 4352 B = 272 KB

  const int nq = in_sizes[0] / DIM;  // 65536
  prep_kernel<<<(KCODES * 8) / BLOCK, BLOCK, 0, stream>>>(cb, cbf);
  vq_mfma<<<nq / 64, BLOCK, 0, stream>>>(z, (const float4*)cb, cbf,
                                         (float4*)d_out);
}

// Round 4
// 108.749 us; speedup vs baseline: 1.0134x; 1.0134x over previous
//
#include <hip/hip_runtime.h>

// VQ nearest-neighbor via f16-split MFMA. N=65536 queries, DIM=64, K=1024.
// v = dot(z,c) - csq[k]/2; argmax_k v  ==  argmin_k ||z-c||^2.
// 2-term f16 split (absmax=0 verified): dot ~= zh.ch + 2^-11(zh.cl'+zl'.ch).
//
// Round-9: A/B isolate on the launch-bounds cap. Rounds 7/8 both pinned
// __launch_bounds__(256,4) (128 unified regs/wave) and both landed at
// VGPR_Count=64 / vq ~51 us regardless of structure: the allocator honors
// the cap by splitting 64 arch VGPR + AGPR and shuttling via
// v_accvgpr_read/write -> VALU 2x model, stretched dep chains, while real
// occupancy measured ~31% (~3 waves/SIMD) anyway. The cap bought nothing.
//  * (256,3): 170-reg budget; the ~115-reg kernel fits in arch VGPRs with
//    no shuttles. Expected VGPR_Count ~130-170 (the theory gate).
//  * unroll 2 on the K-loop: headroom lets iteration t+1's loads fly
//    under iteration t's MFMAs.
//  * Everything else identical to round 8 (csq folded in stream, SGPR
//    tile base, byte-packed bestt, exact tie-break).

typedef _Float16 half8 __attribute__((ext_vector_type(8)));
typedef float float4v __attribute__((ext_vector_type(4)));

constexpr int KCODES = 1024;
constexpr int DIM = 64;
constexpr int BLOCK = 256;

// Tile layout in d_ws (64 tiles of 16 codes each):
//   byte 0..255   : 64 f32, slot (quad*16+m) = -csq[T*16+m]/2 (lane-bcast)
//   byte 256+     : 4 frags x 512 halfs: kt0h, kt0l, kt1h, kt1l
//   frag halfs    : [(quad*16+m)*8 + j], dim = kt*32 + quad*8 + j
constexpr int TILE_BYTES = 4352;

__global__ __launch_bounds__(BLOCK) void prep_kernel(
    const float* __restrict__ cb, char* __restrict__ cbf) {
  const int g = blockIdx.x * BLOCK + threadIdx.x;  // grid 32 x 256 = 8192
  const int k = g >> 3, sub = g & 7;
  const int kt = sub >> 2, quad = sub & 3;
  const int T = k >> 4, m = k & 15;

  const float* src = cb + (size_t)k * DIM + kt * 32 + quad * 8;
  const float4 p0 = ((const float4*)src)[0];
  const float4 p1 = ((const float4*)src)[1];
  const float x[8] = {p0.x, p0.y, p0.z, p0.w, p1.x, p1.y, p1.z, p1.w};

  half8 h8, l8;
  float s = 0.f;
#pragma unroll
  for (int j = 0; j < 8; ++j) {
    s = fmaf(x[j], x[j], s);
    const _Float16 h = (_Float16)x[j];
    h8[j] = h;
    l8[j] = (_Float16)((x[j] - (float)h) * 2048.0f);
  }
  // csq summed over the 8 sub-threads of this code (xor 1/2/4 stays in-wave).
  s += __shfl_xor(s, 1);
  s += __shfl_xor(s, 2);
  s += __shfl_xor(s, 4);

  char* tbase = cbf + (size_t)T * TILE_BYTES;
  if (kt == 0) ((float*)tbase)[quad * 16 + m] = -0.5f * s;  // 4 bcast copies

  _Float16* dst =
      (_Float16*)(tbase + 256) + (size_t)(kt * 2) * 512 + (quad * 16 + m) * 8;
  *(half8*)(dst) = h8;        // hl = 0
  *(half8*)(dst + 512) = l8;  // hl = 1
}

// Block = 256 thr = 4 waves = 1 query-group (64 q) x 4 K-quarters.
__global__ __launch_bounds__(BLOCK, 3) void vq_mfma(
    const float* __restrict__ z, const float4* __restrict__ cb4,
    const char* __restrict__ cbf, float4* __restrict__ out4) {
  __shared__ float rv[4][64];
  __shared__ int rk[4][64];
  __shared__ int sidx[64];

  const int tid = threadIdx.x;
  const int lane = tid & 63;
  const int kh = tid >> 6;    // wave = K quarter (16 tiles = 256 codes)
  const int m = lane & 15;
  const int quad = lane >> 4;

  // A-fragments: 4 qtiles x 2 ktiles, h + l. A[m][k=quad*8+j].
  const int qbase = blockIdx.x * 64;
  half8 ah[4][2], al[4][2];
#pragma unroll
  for (int qt = 0; qt < 4; ++qt) {
    const float* zr = z + (size_t)(qbase + qt * 16 + m) * DIM + quad * 8;
#pragma unroll
    for (int kt = 0; kt < 2; ++kt) {
      const float4 p0 = ((const float4*)(zr + kt * 32))[0];
      const float4 p1 = ((const float4*)(zr + kt * 32))[1];
      const float zf[8] = {p0.x, p0.y, p0.z, p0.w, p1.x, p1.y, p1.z, p1.w};
#pragma unroll
      for (int j = 0; j < 8; ++j) {
        const _Float16 h = (_Float16)zf[j];
        ah[qt][kt][j] = h;
        al[qt][kt][j] = (_Float16)((zf[j] - (float)h) * 2048.0f);
      }
    }
  }

  const float4v zvec = {0.f, 0.f, 0.f, 0.f};
  float best[4][4];
  unsigned bestt[4];  // byte r of bestt[qt] = winning tile id for slot r
#pragma unroll
  for (int qt = 0; qt < 4; ++qt) {
    bestt[qt] = 0u;
#pragma unroll
    for (int r = 0; r < 4; ++r) best[qt][r] = -3.402823466e38f;
  }

  // Wave-uniform tile base (SGPR + SALU bump); per-lane offsets invariant.
  const char* tb = cbf + (size_t)(kh * 16) * TILE_BYTES;
  const int coff = lane * 4;         // c slot
  const int boff = 256 + lane * 16;  // frag base (imm +1024/+2048/+3072)

#pragma unroll 2
  for (int t = 0; t < 16; ++t, tb += TILE_BYTES) {
    const float c = *(const float*)(tb + coff);
    const _Float16* bp = (const _Float16*)(tb + boff);
    const half8 bh0 = *(const half8*)(bp);          // kt0, h
    const half8 bl0 = *(const half8*)(bp + 512);    // kt0, l
    const half8 bh1 = *(const half8*)(bp + 1024);   // kt1, h
    const half8 bl1 = *(const half8*)(bp + 1536);   // kt1, l

    const float4v cvec = {c, c, c, c};
    const unsigned tq = (unsigned)t * 0x01010101u;  // wave-uniform

#pragma unroll
    for (int qt = 0; qt < 4; ++qt) {
      float4v am = __builtin_amdgcn_mfma_f32_16x16x32_f16(ah[qt][0], bh0, cvec, 0, 0, 0);
      am = __builtin_amdgcn_mfma_f32_16x16x32_f16(ah[qt][1], bh1, am, 0, 0, 0);
      float4v ax = __builtin_amdgcn_mfma_f32_16x16x32_f16(ah[qt][0], bl0, zvec, 0, 0, 0);
      ax = __builtin_amdgcn_mfma_f32_16x16x32_f16(ah[qt][1], bl1, ax, 0, 0, 0);
      ax = __builtin_amdgcn_mfma_f32_16x16x32_f16(al[qt][0], bh0, ax, 0, 0, 0);
      ax = __builtin_amdgcn_mfma_f32_16x16x32_f16(al[qt][1], bh1, ax, 0, 0, 0);
#pragma unroll
      for (int r = 0; r < 4; ++r) {
        const float v = fmaf(4.8828125e-4f, ax[r], am[r]);  // 2^-11
        const unsigned mask = 0xFFu << (8 * r);             // compile-time
        const unsigned cand = (bestt[qt] & ~mask) | (tq & mask);  // bfi
        // k ascending in t per lane: strict > keeps lowest-k maximum.
        const bool gt = v > best[qt][r];
        best[qt][r] = gt ? v : best[qt][r];
        bestt[qt] = gt ? cand : bestt[qt];
      }
    }
  }

  // Cross-lane argmax over the 16 cols (m) in each quad; ties -> lower k.
  const int kbase = kh * 256 + m;
#pragma unroll
  for (int qt = 0; qt < 4; ++qt)
#pragma unroll
    for (int r = 0; r < 4; ++r) {
      float b = best[qt][r];
      int bk = kbase + (int)((bestt[qt] >> (8 * r)) & 0xFFu) * 16;
#pragma unroll
      for (int s = 1; s < 16; s <<= 1) {
        const float ob = __shfl_xor(b, s);
        const int obk = __shfl_xor(bk, s);
        if (ob > b || (ob == b && obk < bk)) { b = ob; bk = obk; }
      }
      if (m == 0) {
        const int qb = qt * 16 + quad * 4 + r;  // row = quad*4+r
        rv[kh][qb] = b;
        rk[kh][qb] = bk;
      }
    }
  __syncthreads();

  // Combine K-quarters (strict >: ties -> lower kh = lower k).
  if (tid < 64) {
    float v = rv[0][tid];
    int bk = rk[0][tid];
#pragma unroll
    for (int h = 1; h < 4; ++h) {
      const float vh = rv[h][tid];
      const int kh2 = rk[h][tid];
      if (vh > v) { v = vh; bk = kh2; }
    }
    sidx[tid] = bk;
  }
  __syncthreads();

  // Gather winning fp32 codebook rows; coalesced float4 writes.
  const size_t obase = (size_t)blockIdx.x * 64 * (DIM / 4);
#pragma unroll
  for (int f0 = 0; f0 < 64 * (DIM / 4); f0 += BLOCK) {
    const int f = f0 + tid;
    const int q = f >> 4, e = f & 15;
    out4[obase + f] = cb4[(size_t)sidx[q] * (DIM / 4) + e];
  }
}

extern "C" void kernel_launch(void* const* d_in, const int* in_sizes, int n_in,
                              void* d_out, int out_size, void* d_ws, size_t ws_size,
                              hipStream_t stream) {
  const float* z = (const float*)d_in[0];
  const float* cb = (const float*)d_in[1];
  char* cbf = (char*)d_ws;  // 64 tiles x 4352 B = 272 KB

  const int nq = in_sizes[0] / DIM;  // 65536
  prep_kernel<<<(KCODES * 8) / BLOCK, BLOCK, 0, stream>>>(cb, cbf);
  vq_mfma<<<nq / 64, BLOCK, 0, stream>>>(z, (const float4*)cb, cbf,
                                         (float4*)d_out);
}

// Round 5
// 107.480 us; speedup vs baseline: 1.0254x; 1.0118x over previous
//
#include <hip/hip_runtime.h>

// VQ nearest-neighbor via f16-split MFMA. N=65536 queries, DIM=64, K=1024.
// v = dot(z,c) - csq[k]/2; argmax_k v  ==  argmin_k ||z-c||^2.
//
// Round-10. Post-mortem of rounds 7-9: the 50-52us vq variants all removed
// round-6's explicit 1-deep prefetch; at ~2 waves/SIMD each iteration
// exposed a full L2/L3 load latency (~1950 cyc/iter measured vs ~470 cyc
// MFMA work). Register-cap tuning (256,4)/(256,3) was chasing a ghost.
// This round:
//  * Round-6 structure restored: block = 2 query-groups x 2 K-halves,
//    32-tile K-loop, (256,2), explicit register-rotate prefetch of ALL
//    tile data (7 loads) one iteration ahead.
//  * Scored entirely in the 2^11-SCALED domain via one 6-MFMA C-chain:
//      S' = ((csq' + al'*bh_u) + ah*bl') + ah*bh_s
//    where bh_s = ch*2^11 stored pre-scaled in f16 (exact exponent shift;
//    |ch|*2048 <= ~11k << 65504), bl' = cl*2^11, al' = zl*2^11 (the
//    verified scaling - no subnormal risk), csq' = -2^11*csq/2 folded into
//    the first MFMA's C operand. argmax invariant under positive scale.
//    Per-slot VALU: cmp + 2 selects. No fmaf, no LDS csqn, no barrier,
//    no ds_read in the loop.
//  * B-hi stored twice (unscaled for the al' cross term, scaled for the
//    hi term): tile = 256 B csq + 6 x 1 KB frags = 6400 B. L2 demand
//    ~8 TB/s < 34.5 ceiling.

typedef _Float16 half8 __attribute__((ext_vector_type(8)));
typedef float float4v __attribute__((ext_vector_type(4)));

constexpr int KCODES = 1024;
constexpr int DIM = 64;
constexpr int BLOCK = 256;

// Tile layout in d_ws (64 tiles of 16 codes each), TILE_BYTES = 6400:
//   byte 0..255              : 64 f32, slot (quad*16+m) = -2048*csq[T*16+m]/2
//   byte 256 + kt*3072 + f*1024 + (quad*16+m)*16 : half8 frag
//     f=0: bh_u (ch, f16)   f=1: bh_s (ch*2048)   f=2: bl' (cl*2048)
//   dim = kt*32 + quad*8 + j
constexpr int TILE_BYTES = 6400;

__global__ __launch_bounds__(BLOCK) void prep_kernel(
    const float* __restrict__ cb, char* __restrict__ cbf) {
  const int g = blockIdx.x * BLOCK + threadIdx.x;  // grid 32 x 256 = 8192
  const int k = g >> 3, sub = g & 7;
  const int kt = sub >> 2, quad = sub & 3;
  const int T = k >> 4, m = k & 15;

  const float* src = cb + (size_t)k * DIM + kt * 32 + quad * 8;
  const float4 p0 = ((const float4*)src)[0];
  const float4 p1 = ((const float4*)src)[1];
  const float x[8] = {p0.x, p0.y, p0.z, p0.w, p1.x, p1.y, p1.z, p1.w};

  half8 hu, hs, l8;
  float s = 0.f;
#pragma unroll
  for (int j = 0; j < 8; ++j) {
    s = fmaf(x[j], x[j], s);
    const _Float16 h = (_Float16)x[j];
    hu[j] = h;
    hs[j] = (_Float16)((float)h * 2048.0f);          // exact exponent shift
    l8[j] = (_Float16)((x[j] - (float)h) * 2048.0f); // verified lo scaling
  }
  // csq summed over the 8 sub-threads of this code (xor 1/2/4 stays in-wave).
  s += __shfl_xor(s, 1);
  s += __shfl_xor(s, 2);
  s += __shfl_xor(s, 4);

  char* tbase = cbf + (size_t)T * TILE_BYTES;
  // csq' = 2^11 * (-csq/2); 4 broadcast copies (one per quad slot group).
  if (kt == 0) ((float*)tbase)[quad * 16 + m] = -1024.0f * s;

  _Float16* dst =
      (_Float16*)(tbase + 256 + (size_t)kt * 3072) + (quad * 16 + m) * 8;
  *(half8*)(dst) = hu;          // f=0 bh_u
  *(half8*)(dst + 512) = hs;    // f=1 bh_s
  *(half8*)(dst + 1024) = l8;   // f=2 bl'
}

// Block = 256 thr = 4 waves = 2 query-groups (64 q each) x 2 K-halves.
__global__ __launch_bounds__(BLOCK, 2) void vq_mfma(
    const float* __restrict__ z, const float4* __restrict__ cb4,
    const char* __restrict__ cbf, float4* __restrict__ out4) {
  __shared__ float rv[2][128];
  __shared__ int rk[2][128];
  __shared__ int sidx[128];

  const int tid = threadIdx.x;
  const int lane = tid & 63;
  const int wave = tid >> 6;
  const int qg = wave & 1;    // query group (64 queries)
  const int kh = wave >> 1;   // K half (32 tiles = 512 codes)
  const int m = lane & 15;
  const int quad = lane >> 4;

  // This wave's K-half tile stream; per-lane byte offsets are invariant.
  const char* tb = cbf + (size_t)(kh * 32) * TILE_BYTES;
  const int coff = lane * 4;                // csq' slot
  const int b0 = 256 + lane * 16;           // kt0 frags: +0 / +1024 / +2048
  const int b1 = 256 + 3072 + lane * 16;    // kt1 frags: +0 / +1024 / +2048

  // Prologue prefetch of tile 0 - in flight under the A-fragment build.
  float cnx = *(const float*)(tb + coff);
  half8 nhu0 = *(const half8*)(tb + b0);
  half8 nhs0 = *(const half8*)(tb + b0 + 1024);
  half8 nl0 = *(const half8*)(tb + b0 + 2048);
  half8 nhu1 = *(const half8*)(tb + b1);
  half8 nhs1 = *(const half8*)(tb + b1 + 1024);
  half8 nl1 = *(const half8*)(tb + b1 + 2048);

  // A-fragments: 4 qtiles x 2 ktiles, h + l'. A[m][k=quad*8+j].
  const int qbase = blockIdx.x * 128 + qg * 64;
  half8 ah[4][2], al[4][2];
#pragma unroll
  for (int qt = 0; qt < 4; ++qt) {
    const float* zr = z + (size_t)(qbase + qt * 16 + m) * DIM + quad * 8;
#pragma unroll
    for (int kt = 0; kt < 2; ++kt) {
      const float4 p0 = ((const float4*)(zr + kt * 32))[0];
      const float4 p1 = ((const float4*)(zr + kt * 32))[1];
      const float zf[8] = {p0.x, p0.y, p0.z, p0.w, p1.x, p1.y, p1.z, p1.w};
#pragma unroll
      for (int j = 0; j < 8; ++j) {
        const _Float16 h = (_Float16)zf[j];
        ah[qt][kt][j] = h;
        al[qt][kt][j] = (_Float16)((zf[j] - (float)h) * 2048.0f);
      }
    }
  }

  float best[4][4];
  unsigned bestt[4];  // byte r of bestt[qt] = winning tile id (0..31)
#pragma unroll
  for (int qt = 0; qt < 4; ++qt) {
    bestt[qt] = 0u;
#pragma unroll
    for (int r = 0; r < 4; ++r) best[qt][r] = -3.402823466e38f;
  }

  const char* tbn = tb + TILE_BYTES;  // prefetch pointer (1 tile ahead)
#pragma unroll 2
  for (int t = 0; t < 32; ++t, tbn += TILE_BYTES) {
    // Rotate in the tile prefetched last iteration.
    const half8 hu0 = nhu0, hs0 = nhs0, l0 = nl0;
    const half8 hu1 = nhu1, hs1 = nhs1, l1 = nl1;
    const float c = cnx;

    // Prefetch tile t+1 (last iteration reads past our K-half: harmless,
    // stays inside the 256 MiB workspace, values never consumed).
    cnx = *(const float*)(tbn + coff);
    nhu0 = *(const half8*)(tbn + b0);
    nhs0 = *(const half8*)(tbn + b0 + 1024);
    nl0 = *(const half8*)(tbn + b0 + 2048);
    nhu1 = *(const half8*)(tbn + b1);
    nhs1 = *(const half8*)(tbn + b1 + 1024);
    nl1 = *(const half8*)(tbn + b1 + 2048);

    const float4v cvec = {c, c, c, c};
    const unsigned tq = (unsigned)t * 0x01010101u;  // wave-uniform

#pragma unroll
    for (int qt = 0; qt < 4; ++qt) {
      // S' = ((csq' + al'*bh_u) + ah*bl') + ah*bh_s   (all 2^11-scaled)
      float4v S = __builtin_amdgcn_mfma_f32_16x16x32_f16(al[qt][0], hu0, cvec, 0, 0, 0);
      S = __builtin_amdgcn_mfma_f32_16x16x32_f16(al[qt][1], hu1, S, 0, 0, 0);
      S = __builtin_amdgcn_mfma_f32_16x16x32_f16(ah[qt][0], l0, S, 0, 0, 0);
      S = __builtin_amdgcn_mfma_f32_16x16x32_f16(ah[qt][1], l1, S, 0, 0, 0);
      S = __builtin_amdgcn_mfma_f32_16x16x32_f16(ah[qt][0], hs0, S, 0, 0, 0);
      S = __builtin_amdgcn_mfma_f32_16x16x32_f16(ah[qt][1], hs1, S, 0, 0, 0);
#pragma unroll
      for (int r = 0; r < 4; ++r) {
        const unsigned mask = 0xFFu << (8 * r);                   // imm
        const unsigned cand = (bestt[qt] & ~mask) | (tq & mask);  // bfi
        // t ascending per lane: strict > keeps lowest-k maximum.
        const bool gt = S[r] > best[qt][r];
        best[qt][r] = gt ? S[r] : best[qt][r];
        bestt[qt] = gt ? cand : bestt[qt];
      }
    }
  }

  // Cross-lane argmax over the 16 cols (m) in each quad; ties -> lower k.
  const int kbase = kh * 512 + m;
#pragma unroll
  for (int qt = 0; qt < 4; ++qt)
#pragma unroll
    for (int r = 0; r < 4; ++r) {
      float b = best[qt][r];
      int bk = kbase + (int)((bestt[qt] >> (8 * r)) & 0xFFu) * 16;
#pragma unroll
      for (int s = 1; s < 16; s <<= 1) {
        const float ob = __shfl_xor(b, s);
        const int obk = __shfl_xor(bk, s);
        if (ob > b || (ob == b && obk < bk)) { b = ob; bk = obk; }
      }
      if (m == 0) {
        const int qb = qg * 64 + qt * 16 + quad * 4 + r;  // row = quad*4+r
        rv[kh][qb] = b;
        rk[kh][qb] = bk;
      }
    }
  __syncthreads();

  // Combine K-halves (strict >: ties -> half 0 = lower k).
  if (tid < 128) {
    const float v0 = rv[0][tid], v1 = rv[1][tid];
    sidx[tid] = (v1 > v0) ? rk[1][tid] : rk[0][tid];
  }
  __syncthreads();

  // Gather winning fp32 codebook rows; coalesced float4 writes.
  const size_t obase = (size_t)blockIdx.x * 128 * (DIM / 4);
#pragma unroll
  for (int f0 = 0; f0 < 128 * (DIM / 4); f0 += BLOCK) {
    const int f = f0 + tid;
    const int q = f >> 4, e = f & 15;
    out4[obase + f] = cb4[(size_t)sidx[q] * (DIM / 4) + e];
  }
}

extern "C" void kernel_launch(void* const* d_in, const int* in_sizes, int n_in,
                              void* d_out, int out_size, void* d_ws, size_t ws_size,
                              hipStream_t stream) {
  const float* z = (const float*)d_in[0];
  const float* cb = (const float*)d_in[1];
  char* cbf = (char*)d_ws;  // 64 tiles x 6400 B = 400 KB

  const int nq = in_sizes[0] / DIM;  // 65536
  prep_kernel<<<(KCODES * 8) / BLOCK, BLOCK, 0, stream>>>(cb, cbf);
  vq_mfma<<<nq / 128, BLOCK, 0, stream>>>(z, (const float4*)cb, cbf,
                                          (float4*)d_out);
}

// Round 6
// 106.217 us; speedup vs baseline: 1.0376x; 1.0119x over previous
//
#include <hip/hip_runtime.h>

// VQ nearest-neighbor via f16-split MFMA. N=65536 queries, DIM=64, K=1024.
// v = dot(z,c) - csq[k]/2; argmax_k v  ==  argmin_k ||z-c||^2.
//
// Round-11. Round-10 post-mortem: vq 46.4us, 1736 cy/SIMD/wave-iter vs
// ~390 cy matrix content. Measured VALU = ~453 cy/iter (~226 wave64 inst)
// = the per-slot argmax epilogue (byte-packed bestt: cmp + cndmask + bfi
// and/or + cndmask per slot, 5-deep dep chain hanging off each MFMA
// chain's tail, issued in-order ahead of the next iteration's MFMAs).
// This round, ONE change: bestt unpacked to 16 full u32 regs so the
// per-slot update is exactly {v_cmp_gt, v_max_f32, v_cndmask(t from
// SGPR)} - 3 inst, 2-deep. ~450 -> ~150 cy/iter of VALU. Costs 12 VGPRs
// (irrelevant at (256,2)). Tie-break identical: strict >, ties keep old
// (lower t -> lower k).
//
// Carried from round 10:
//  * block = 2 query-groups x 2 K-halves, 32-tile K-loop, (256,2),
//    explicit register-rotate prefetch of all 7 tile loads 1 iter ahead.
//  * 2^11-scaled scoring in one 6-MFMA C-chain:
//      S' = ((csq' + al'*bh_u) + ah*bl') + ah*bh_s
//    bh_s = ch*2048 (exact f16 exponent shift), bl' = cl*2048,
//    al' = zl*2048, csq' = -1024*csq folded into the first C operand.
//    argmax invariant under the positive scale. No fmaf, no LDS csqn,
//    no barrier, no ds_read in the loop.

typedef _Float16 half8 __attribute__((ext_vector_type(8)));
typedef float float4v __attribute__((ext_vector_type(4)));

constexpr int KCODES = 1024;
constexpr int DIM = 64;
constexpr int BLOCK = 256;

// Tile layout in d_ws (64 tiles of 16 codes each), TILE_BYTES = 6400:
//   byte 0..255              : 64 f32, slot (quad*16+m) = -2048*csq[T*16+m]/2
//   byte 256 + kt*3072 + f*1024 + (quad*16+m)*16 : half8 frag
//     f=0: bh_u (ch, f16)   f=1: bh_s (ch*2048)   f=2: bl' (cl*2048)
//   dim = kt*32 + quad*8 + j
constexpr int TILE_BYTES = 6400;

__global__ __launch_bounds__(BLOCK) void prep_kernel(
    const float* __restrict__ cb, char* __restrict__ cbf) {
  const int g = blockIdx.x * BLOCK + threadIdx.x;  // grid 32 x 256 = 8192
  const int k = g >> 3, sub = g & 7;
  const int kt = sub >> 2, quad = sub & 3;
  const int T = k >> 4, m = k & 15;

  const float* src = cb + (size_t)k * DIM + kt * 32 + quad * 8;
  const float4 p0 = ((const float4*)src)[0];
  const float4 p1 = ((const float4*)src)[1];
  const float x[8] = {p0.x, p0.y, p0.z, p0.w, p1.x, p1.y, p1.z, p1.w};

  half8 hu, hs, l8;
  float s = 0.f;
#pragma unroll
  for (int j = 0; j < 8; ++j) {
    s = fmaf(x[j], x[j], s);
    const _Float16 h = (_Float16)x[j];
    hu[j] = h;
    hs[j] = (_Float16)((float)h * 2048.0f);          // exact exponent shift
    l8[j] = (_Float16)((x[j] - (float)h) * 2048.0f); // verified lo scaling
  }
  // csq summed over the 8 sub-threads of this code (xor 1/2/4 stays in-wave).
  s += __shfl_xor(s, 1);
  s += __shfl_xor(s, 2);
  s += __shfl_xor(s, 4);

  char* tbase = cbf + (size_t)T * TILE_BYTES;
  // csq' = 2^11 * (-csq/2); 4 broadcast copies (one per quad slot group).
  if (kt == 0) ((float*)tbase)[quad * 16 + m] = -1024.0f * s;

  _Float16* dst =
      (_Float16*)(tbase + 256 + (size_t)kt * 3072) + (quad * 16 + m) * 8;
  *(half8*)(dst) = hu;          // f=0 bh_u
  *(half8*)(dst + 512) = hs;    // f=1 bh_s
  *(half8*)(dst + 1024) = l8;   // f=2 bl'
}

// Block = 256 thr = 4 waves = 2 query-groups (64 q each) x 2 K-halves.
__global__ __launch_bounds__(BLOCK, 2) void vq_mfma(
    const float* __restrict__ z, const float4* __restrict__ cb4,
    const char* __restrict__ cbf, float4* __restrict__ out4) {
  __shared__ float rv[2][128];
  __shared__ int rk[2][128];
  __shared__ int sidx[128];

  const int tid = threadIdx.x;
  const int lane = tid & 63;
  const int wave = tid >> 6;
  const int qg = wave & 1;    // query group (64 queries)
  const int kh = wave >> 1;   // K half (32 tiles = 512 codes)
  const int m = lane & 15;
  const int quad = lane >> 4;

  // This wave's K-half tile stream; per-lane byte offsets are invariant.
  const char* tb = cbf + (size_t)(kh * 32) * TILE_BYTES;
  const int coff = lane * 4;                // csq' slot
  const int b0 = 256 + lane * 16;           // kt0 frags: +0 / +1024 / +2048
  const int b1 = 256 + 3072 + lane * 16;    // kt1 frags: +0 / +1024 / +2048

  // Prologue prefetch of tile 0 - in flight under the A-fragment build.
  float cnx = *(const float*)(tb + coff);
  half8 nhu0 = *(const half8*)(tb + b0);
  half8 nhs0 = *(const half8*)(tb + b0 + 1024);
  half8 nl0 = *(const half8*)(tb + b0 + 2048);
  half8 nhu1 = *(const half8*)(tb + b1);
  half8 nhs1 = *(const half8*)(tb + b1 + 1024);
  half8 nl1 = *(const half8*)(tb + b1 + 2048);

  // A-fragments: 4 qtiles x 2 ktiles, h + l'. A[m][k=quad*8+j].
  const int qbase = blockIdx.x * 128 + qg * 64;
  half8 ah[4][2], al[4][2];
#pragma unroll
  for (int qt = 0; qt < 4; ++qt) {
    const float* zr = z + (size_t)(qbase + qt * 16 + m) * DIM + quad * 8;
#pragma unroll
    for (int kt = 0; kt < 2; ++kt) {
      const float4 p0 = ((const float4*)(zr + kt * 32))[0];
      const float4 p1 = ((const float4*)(zr + kt * 32))[1];
      const float zf[8] = {p0.x, p0.y, p0.z, p0.w, p1.x, p1.y, p1.z, p1.w};
#pragma unroll
      for (int j = 0; j < 8; ++j) {
        const _Float16 h = (_Float16)zf[j];
        ah[qt][kt][j] = h;
        al[qt][kt][j] = (_Float16)((zf[j] - (float)h) * 2048.0f);
      }
    }
  }

  float best[4][4];
  int bestt[4][4];  // winning tile id (0..31), full u32 per slot
#pragma unroll
  for (int qt = 0; qt < 4; ++qt)
#pragma unroll
    for (int r = 0; r < 4; ++r) {
      best[qt][r] = -3.402823466e38f;
      bestt[qt][r] = 0;
    }

  const char* tbn = tb + TILE_BYTES;  // prefetch pointer (1 tile ahead)
#pragma unroll 2
  for (int t = 0; t < 32; ++t, tbn += TILE_BYTES) {
    // Rotate in the tile prefetched last iteration.
    const half8 hu0 = nhu0, hs0 = nhs0, l0 = nl0;
    const half8 hu1 = nhu1, hs1 = nhs1, l1 = nl1;
    const float c = cnx;

    // Prefetch tile t+1 (last iteration reads past our K-half: harmless,
    // stays inside the 256 MiB workspace, values never consumed).
    cnx = *(const float*)(tbn + coff);
    nhu0 = *(const half8*)(tbn + b0);
    nhs0 = *(const half8*)(tbn + b0 + 1024);
    nl0 = *(const half8*)(tbn + b0 + 2048);
    nhu1 = *(const half8*)(tbn + b1);
    nhs1 = *(const half8*)(tbn + b1 + 1024);
    nl1 = *(const half8*)(tbn + b1 + 2048);

    const float4v cvec = {c, c, c, c};

#pragma unroll
    for (int qt = 0; qt < 4; ++qt) {
      // S' = ((csq' + al'*bh_u) + ah*bl') + ah*bh_s   (all 2^11-scaled)
      float4v S = __builtin_amdgcn_mfma_f32_16x16x32_f16(al[qt][0], hu0, cvec, 0, 0, 0);
      S = __builtin_amdgcn_mfma_f32_16x16x32_f16(al[qt][1], hu1, S, 0, 0, 0);
      S = __builtin_amdgcn_mfma_f32_16x16x32_f16(ah[qt][0], l0, S, 0, 0, 0);
      S = __builtin_amdgcn_mfma_f32_16x16x32_f16(ah[qt][1], l1, S, 0, 0, 0);
      S = __builtin_amdgcn_mfma_f32_16x16x32_f16(ah[qt][0], hs0, S, 0, 0, 0);
      S = __builtin_amdgcn_mfma_f32_16x16x32_f16(ah[qt][1], hs1, S, 0, 0, 0);
#pragma unroll
      for (int r = 0; r < 4; ++r) {
        // 3 inst: v_cmp_gt / v_max_f32 / v_cndmask (t wave-uniform SGPR).
        // t ascending per lane + strict > keeps lowest-k maximum.
        const bool gt = S[r] > best[qt][r];
        best[qt][r] = fmaxf(S[r], best[qt][r]);
        bestt[qt][r] = gt ? t : bestt[qt][r];
      }
    }
  }

  // Cross-lane argmax over the 16 cols (m) in each quad; ties -> lower k.
  const int kbase = kh * 512 + m;
#pragma unroll
  for (int qt = 0; qt < 4; ++qt)
#pragma unroll
    for (int r = 0; r < 4; ++r) {
      float b = best[qt][r];
      int bk = kbase + bestt[qt][r] * 16;
#pragma unroll
      for (int s = 1; s < 16; s <<= 1) {
        const float ob = __shfl_xor(b, s);
        const int obk = __shfl_xor(bk, s);
        if (ob > b || (ob == b && obk < bk)) { b = ob; bk = obk; }
      }
      if (m == 0) {
        const int qb = qg * 64 + qt * 16 + quad * 4 + r;  // row = quad*4+r
        rv[kh][qb] = b;
        rk[kh][qb] = bk;
      }
    }
  __syncthreads();

  // Combine K-halves (strict >: ties -> half 0 = lower k).
  if (tid < 128) {
    const float v0 = rv[0][tid], v1 = rv[1][tid];
    sidx[tid] = (v1 > v0) ? rk[1][tid] : rk[0][tid];
  }
  __syncthreads();

  // Gather winning fp32 codebook rows; coalesced float4 writes.
  const size_t obase = (size_t)blockIdx.x * 128 * (DIM / 4);
#pragma unroll
  for (int f0 = 0; f0 < 128 * (DIM / 4); f0 += BLOCK) {
    const int f = f0 + tid;
    const int q = f >> 4, e = f & 15;
    out4[obase + f] = cb4[(size_t)sidx[q] * (DIM / 4) + e];
  }
}

extern "C" void kernel_launch(void* const* d_in, const int* in_sizes, int n_in,
                              void* d_out, int out_size, void* d_ws, size_t ws_size,
                              hipStream_t stream) {
  const float* z = (const float*)d_in[0];
  const float* cb = (const float*)d_in[1];
  char* cbf = (char*)d_ws;  // 64 tiles x 6400 B = 400 KB

  const int nq = in_sizes[0] / DIM;  // 65536
  prep_kernel<<<(KCODES * 8) / BLOCK, BLOCK, 0, stream>>>(cb, cbf);
  vq_mfma<<<nq / 128, BLOCK, 0, stream>>>(z, (const float4*)cb, cbf,
                                          (float4*)d_out);
}

// Round 8
// 105.833 us; speedup vs baseline: 1.0413x; 1.0036x over previous
//
#include <hip/hip_runtime.h>

// VQ nearest-neighbor via f16-split MFMA. N=65536 queries, DIM=64, K=1024.
// v = dot(z,c) - csq[k]/2; argmax_k v  ==  argmin_k ||z-c||^2.
//
// Round-13 = round-12 resubmitted (bench infra failed twice; no result).
// Theory under test (from round-11 post-mortem): per-iter accounting is
// ~470 cy matrix + ~1200 cy STALL caused by the lockstep convoy. All 512
// blocks run in one round, sweeping tiles in identical order; the 256 MiB
// poison flushed every L2, so at each step all ~64 blocks/XCD demand the
// same tile: one cold miss (~600-900 cy) + everyone else hit-under-miss.
// Fixes:
//  * Rotated sweep: block starts at tile (blockIdx.x>>3)&31, wraps mod 32.
//    Co-resident blocks touch different tiles -> first toucher pays the
//    miss once, the rest hit warm L2 (~200cy). Max is order-independent;
//    exact lowest-k ties kept via explicit (S==best && tt<bestt) term.
//  * Prefetch depth 2 (two tile-register buffers; A-loads issued first)
//    to cover residual first-toucher misses with ~2 iterations of work.
//
// Carried: 2^11-scaled 6-MFMA C-chain scoring
//   S' = ((csq' + al'*bh_u) + ah*bl') + ah*bh_s
// (bh_s = ch*2048 exact f16 exponent shift, bl' = cl*2048, al' = zl*2048,
//  csq' = -1024*csq in the first C operand), (256,2), no LDS/barrier/
//  ds_read in the loop.

typedef _Float16 half8 __attribute__((ext_vector_type(8)));
typedef float float4v __attribute__((ext_vector_type(4)));

constexpr int KCODES = 1024;
constexpr int DIM = 64;
constexpr int BLOCK = 256;

// Tile layout in d_ws (64 tiles of 16 codes each), TILE_BYTES = 6400:
//   byte 0..255              : 64 f32, slot (quad*16+m) = -2048*csq[T*16+m]/2
//   byte 256 + kt*3072 + f*1024 + (quad*16+m)*16 : half8 frag
//     f=0: bh_u (ch, f16)   f=1: bh_s (ch*2048)   f=2: bl' (cl*2048)
//   dim = kt*32 + quad*8 + j
constexpr int TILE_BYTES = 6400;

__global__ __launch_bounds__(BLOCK) void prep_kernel(
    const float* __restrict__ cb, char* __restrict__ cbf) {
  const int g = blockIdx.x * BLOCK + threadIdx.x;  // grid 32 x 256 = 8192
  const int k = g >> 3, sub = g & 7;
  const int kt = sub >> 2, quad = sub & 3;
  const int T = k >> 4, m = k & 15;

  const float* src = cb + (size_t)k * DIM + kt * 32 + quad * 8;
  const float4 p0 = ((const float4*)src)[0];
  const float4 p1 = ((const float4*)src)[1];
  const float x[8] = {p0.x, p0.y, p0.z, p0.w, p1.x, p1.y, p1.z, p1.w};

  half8 hu, hs, l8;
  float s = 0.f;
#pragma unroll
  for (int j = 0; j < 8; ++j) {
    s = fmaf(x[j], x[j], s);
    const _Float16 h = (_Float16)x[j];
    hu[j] = h;
    hs[j] = (_Float16)((float)h * 2048.0f);          // exact exponent shift
    l8[j] = (_Float16)((x[j] - (float)h) * 2048.0f); // verified lo scaling
  }
  // csq summed over the 8 sub-threads of this code (xor 1/2/4 stays in-wave).
  s += __shfl_xor(s, 1);
  s += __shfl_xor(s, 2);
  s += __shfl_xor(s, 4);

  char* tbase = cbf + (size_t)T * TILE_BYTES;
  // csq' = 2^11 * (-csq/2); 4 broadcast copies (one per quad slot group).
  if (kt == 0) ((float*)tbase)[quad * 16 + m] = -1024.0f * s;

  _Float16* dst =
      (_Float16*)(tbase + 256 + (size_t)kt * 3072) + (quad * 16 + m) * 8;
  *(half8*)(dst) = hu;          // f=0 bh_u
  *(half8*)(dst + 512) = hs;    // f=1 bh_s
  *(half8*)(dst + 1024) = l8;   // f=2 bl'
}

struct TileRegs {
  float c;
  half8 hu0, hs0, l0, hu1, hs1, l1;
};

// Block = 256 thr = 4 waves = 2 query-groups (64 q each) x 2 K-halves.
__global__ __launch_bounds__(BLOCK, 2) void vq_mfma(
    const float* __restrict__ z, const float4* __restrict__ cb4,
    const char* __restrict__ cbf, float4* __restrict__ out4) {
  __shared__ float rv[2][128];
  __shared__ int rk[2][128];
  __shared__ int sidx[128];

  const int tid = threadIdx.x;
  const int lane = tid & 63;
  const int wave = tid >> 6;
  const int qg = wave & 1;    // query group (64 queries)
  const int kh = wave >> 1;   // K half (32 tiles = 512 codes)
  const int m = lane & 15;
  const int quad = lane >> 4;

  const char* tbk = cbf + (size_t)(kh * 32) * TILE_BYTES;
  const int coff = lane * 4;                // csq' slot
  const int b0 = 256 + lane * 16;           // kt0 frags: +0 / +1024 / +2048
  const int b1 = 256 + 3072 + lane * 16;    // kt1 frags: +0 / +1024 / +2048

  auto loadTile = [&](int toff) {
    const char* p = tbk + (size_t)toff * TILE_BYTES;
    TileRegs r;
    r.c = *(const float*)(p + coff);
    r.hu0 = *(const half8*)(p + b0);
    r.hs0 = *(const half8*)(p + b0 + 1024);
    r.l0 = *(const half8*)(p + b0 + 2048);
    r.hu1 = *(const half8*)(p + b1);
    r.hs1 = *(const half8*)(p + b1 + 1024);
    r.l1 = *(const half8*)(p + b1 + 2048);
    return r;
  };

  // A-row loads FIRST (their conversion work below covers tile-load flight).
  const int qbase = blockIdx.x * 128 + qg * 64;
  float4 zp[4][2][2];
#pragma unroll
  for (int qt = 0; qt < 4; ++qt) {
    const float* zr = z + (size_t)(qbase + qt * 16 + m) * DIM + quad * 8;
#pragma unroll
    for (int kt = 0; kt < 2; ++kt) {
      zp[qt][kt][0] = ((const float4*)(zr + kt * 32))[0];
      zp[qt][kt][1] = ((const float4*)(zr + kt * 32))[1];
    }
  }

  // Rotated start tile: co-resident blocks touch different tiles.
  const int t0 = (blockIdx.x >> 3) & 31;

  // Depth-2 prologue: tiles seq(0), seq(1) in flight.
  TileRegs buf0 = loadTile(t0);
  TileRegs buf1 = loadTile((t0 + 1) & 31);

  // A-fragments: 4 qtiles x 2 ktiles, h + l'. A[m][k=quad*8+j].
  half8 ah[4][2], al[4][2];
#pragma unroll
  for (int qt = 0; qt < 4; ++qt)
#pragma unroll
    for (int kt = 0; kt < 2; ++kt) {
      const float4 p0 = zp[qt][kt][0];
      const float4 p1 = zp[qt][kt][1];
      const float zf[8] = {p0.x, p0.y, p0.z, p0.w, p1.x, p1.y, p1.z, p1.w};
#pragma unroll
      for (int j = 0; j < 8; ++j) {
        const _Float16 h = (_Float16)zf[j];
        ah[qt][kt][j] = h;
        al[qt][kt][j] = (_Float16)((zf[j] - (float)h) * 2048.0f);
      }
    }

  float best[4][4];
  int bestt[4][4];  // winning tile id (0..31)
#pragma unroll
  for (int qt = 0; qt < 4; ++qt)
#pragma unroll
    for (int r = 0; r < 4; ++r) {
      best[qt][r] = -3.402823466e38f;
      bestt[qt][r] = 0;
    }

  int tc = t0;             // tile consumed by the even slot this iteration
  int tp = (t0 + 2) & 31;  // tile to prefetch into the consumed buffer

#pragma unroll 1
  for (int i = 0; i < 16; ++i) {
    // ---- even slot: consume buf0 (tile tc), refill with tile tp ----
    {
      float4v S[4];
#pragma unroll
      for (int qt = 0; qt < 4; ++qt) {
        const float4v cvec = {buf0.c, buf0.c, buf0.c, buf0.c};
        float4v s_ = __builtin_amdgcn_mfma_f32_16x16x32_f16(al[qt][0], buf0.hu0, cvec, 0, 0, 0);
        s_ = __builtin_amdgcn_mfma_f32_16x16x32_f16(al[qt][1], buf0.hu1, s_, 0, 0, 0);
        s_ = __builtin_amdgcn_mfma_f32_16x16x32_f16(ah[qt][0], buf0.l0, s_, 0, 0, 0);
        s_ = __builtin_amdgcn_mfma_f32_16x16x32_f16(ah[qt][1], buf0.l1, s_, 0, 0, 0);
        s_ = __builtin_amdgcn_mfma_f32_16x16x32_f16(ah[qt][0], buf0.hs0, s_, 0, 0, 0);
        s_ = __builtin_amdgcn_mfma_f32_16x16x32_f16(ah[qt][1], buf0.hs1, s_, 0, 0, 0);
        S[qt] = s_;
      }
      buf0 = loadTile(tp);  // issued after the consuming MFMAs
#pragma unroll
      for (int qt = 0; qt < 4; ++qt)
#pragma unroll
        for (int r = 0; r < 4; ++r) {
          // Exact lowest-k tie-break under rotation: within a lane (fixed
          // m), lower tile id == lower k.
          const bool gt = (S[qt][r] > best[qt][r]) ||
                          (S[qt][r] == best[qt][r] && tc < bestt[qt][r]);
          best[qt][r] = gt ? S[qt][r] : best[qt][r];
          bestt[qt][r] = gt ? tc : bestt[qt][r];
        }
      tc = (tc + 1) & 31;
      tp = (tp + 1) & 31;
    }
    // ---- odd slot: consume buf1 (tile tc), refill with tile tp ----
    {
      float4v S[4];
#pragma unroll
      for (int qt = 0; qt < 4; ++qt) {
        const float4v cvec = {buf1.c, buf1.c, buf1.c, buf1.c};
        float4v s_ = __builtin_amdgcn_mfma_f32_16x16x32_f16(al[qt][0], buf1.hu0, cvec, 0, 0, 0);
        s_ = __builtin_amdgcn_mfma_f32_16x16x32_f16(al[qt][1], buf1.hu1, s_, 0, 0, 0);
        s_ = __builtin_amdgcn_mfma_f32_16x16x32_f16(ah[qt][0], buf1.l0, s_, 0, 0, 0);
        s_ = __builtin_amdgcn_mfma_f32_16x16x32_f16(ah[qt][1], buf1.l1, s_, 0, 0, 0);
        s_ = __builtin_amdgcn_mfma_f32_16x16x32_f16(ah[qt][0], buf1.hs0, s_, 0, 0, 0);
        s_ = __builtin_amdgcn_mfma_f32_16x16x32_f16(ah[qt][1], buf1.hs1, s_, 0, 0, 0);
        S[qt] = s_;
      }
      buf1 = loadTile(tp);
#pragma unroll
      for (int qt = 0; qt < 4; ++qt)
#pragma unroll
        for (int r = 0; r < 4; ++r) {
          const bool gt = (S[qt][r] > best[qt][r]) ||
                          (S[qt][r] == best[qt][r] && tc < bestt[qt][r]);
          best[qt][r] = gt ? S[qt][r] : best[qt][r];
          bestt[qt][r] = gt ? tc : bestt[qt][r];
        }
      tc = (tc + 1) & 31;
      tp = (tp + 1) & 31;
    }
  }

  // Cross-lane argmax over the 16 cols (m) in each quad; ties -> lower k.
  const int kbase = kh * 512 + m;
#pragma unroll
  for (int qt = 0; qt < 4; ++qt)
#pragma unroll
    for (int r = 0; r < 4; ++r) {
      float b = best[qt][r];
      int bk = kbase + bestt[qt][r] * 16;
#pragma unroll
      for (int s = 1; s < 16; s <<= 1) {
        const float ob = __shfl_xor(b, s);
        const int obk = __shfl_xor(bk, s);
        if (ob > b || (ob == b && obk < bk)) { b = ob; bk = obk; }
      }
      if (m == 0) {
        const int qb = qg * 64 + qt * 16 + quad * 4 + r;  // row = quad*4+r
        rv[kh][qb] = b;
        rk[kh][qb] = bk;
      }
    }
  __syncthreads();

  // Combine K-halves (strict >; value ties -> lower k).
  if (tid < 128) {
    const float v0 = rv[0][tid], v1 = rv[1][tid];
    const int k0 = rk[0][tid], k1 = rk[1][tid];
    sidx[tid] = (v1 > v0 || (v1 == v0 && k1 < k0)) ? k1 : k0;
  }
  __syncthreads();

  // Gather winning fp32 codebook rows; coalesced float4 writes.
  const size_t obase = (size_t)blockIdx.x * 128 * (DIM / 4);
#pragma unroll
  for (int f0 = 0; f0 < 128 * (DIM / 4); f0 += BLOCK) {
    const int f = f0 + tid;
    const int q = f >> 4, e = f & 15;
    out4[obase + f] = cb4[(size_t)sidx[q] * (DIM / 4) + e];
  }
}

extern "C" void kernel_launch(void* const* d_in, const int* in_sizes, int n_in,
                              void* d_out, int out_size, void* d_ws, size_t ws_size,
                              hipStream_t stream) {
  const float* z = (const float*)d_in[0];
  const float* cb = (const float*)d_in[1];
  char* cbf = (char*)d_ws;  // 64 tiles x 6400 B = 400 KB

  const int nq = in_sizes[0] / DIM;  // 65536
  prep_kernel<<<(KCODES * 8) / BLOCK, BLOCK, 0, stream>>>(cb, cbf);
  vq_mfma<<<nq / 128, BLOCK, 0, stream>>>(z, (const float4*)cb, cbf,
                                          (float4*)d_out);
}

// Round 9
// 101.947 us; speedup vs baseline: 1.0810x; 1.0381x over previous
//
#include <hip/hip_runtime.h>

// VQ nearest-neighbor via f16-split MFMA. N=65536 queries, DIM=64, K=1024.
// v = dot(z,c) - csq[k]/2; argmax_k v  ==  argmin_k ||z-c||^2.
//
// Round-14. Ledger: MfmaUtil pinned 19-21% across occupancy 18-31%, VGPR
// 64-96, prefetch depth 0/1/2, csqn-in-LDS vs in-stream, rotated vs
// lockstep sweep. Memory exonerated (FETCH 10.7MB, conflicts 0, HBM 7%).
// Per-SIMD: 3360 cy/tile-iter (2 waves) vs ~930 cy MFMA issue content.
// Remaining invariant: four 6-deep serially C-dependent MFMA chains per
// wave. Hypothesis: dependent-issue latency of mfma_16x16x32_f16 is
// ~100-150cy; 6 links x latency = the stall. Evidence: round-1 (max depth
// 4) ran vq ~40us; all 6-deep variants 45-52us.
// ONE change vs the best kernel (round-6/11, 44.8us): split each qt's
// 6-chain into TWO INDEPENDENT 3-chains (kt0 seeded with csq', kt1 seeded
// 0), combined by one v_add_f32 per slot. Chains/wave 4->8, depth 6->3,
// same MFMA count, same A-regs. Rotation/depth-2 reverted (47.1 > 44.8).
//
// Carried from round 11: 2^11-scaled scoring (bh_s = ch*2048 exact f16
// exponent shift, bl' = cl*2048, al' = zl*2048, csq' = -1024*csq in the
// kt0 chain's C operand), (256,2), 1-deep register-rotate prefetch, no
// LDS/barrier/ds_read in the K-loop, 3-inst argmax epilogue.

typedef _Float16 half8 __attribute__((ext_vector_type(8)));
typedef float float4v __attribute__((ext_vector_type(4)));

constexpr int KCODES = 1024;
constexpr int DIM = 64;
constexpr int BLOCK = 256;

// Tile layout in d_ws (64 tiles of 16 codes each), TILE_BYTES = 6400:
//   byte 0..255              : 64 f32, slot (quad*16+m) = -2048*csq[T*16+m]/2
//   byte 256 + kt*3072 + f*1024 + (quad*16+m)*16 : half8 frag
//     f=0: bh_u (ch, f16)   f=1: bh_s (ch*2048)   f=2: bl' (cl*2048)
//   dim = kt*32 + quad*8 + j
constexpr int TILE_BYTES = 6400;

__global__ __launch_bounds__(BLOCK) void prep_kernel(
    const float* __restrict__ cb, char* __restrict__ cbf) {
  const int g = blockIdx.x * BLOCK + threadIdx.x;  // grid 32 x 256 = 8192
  const int k = g >> 3, sub = g & 7;
  const int kt = sub >> 2, quad = sub & 3;
  const int T = k >> 4, m = k & 15;

  const float* src = cb + (size_t)k * DIM + kt * 32 + quad * 8;
  const float4 p0 = ((const float4*)src)[0];
  const float4 p1 = ((const float4*)src)[1];
  const float x[8] = {p0.x, p0.y, p0.z, p0.w, p1.x, p1.y, p1.z, p1.w};

  half8 hu, hs, l8;
  float s = 0.f;
#pragma unroll
  for (int j = 0; j < 8; ++j) {
    s = fmaf(x[j], x[j], s);
    const _Float16 h = (_Float16)x[j];
    hu[j] = h;
    hs[j] = (_Float16)((float)h * 2048.0f);          // exact exponent shift
    l8[j] = (_Float16)((x[j] - (float)h) * 2048.0f); // verified lo scaling
  }
  // csq summed over the 8 sub-threads of this code (xor 1/2/4 stays in-wave).
  s += __shfl_xor(s, 1);
  s += __shfl_xor(s, 2);
  s += __shfl_xor(s, 4);

  char* tbase = cbf + (size_t)T * TILE_BYTES;
  // csq' = 2^11 * (-csq/2); 4 broadcast copies (one per quad slot group).
  if (kt == 0) ((float*)tbase)[quad * 16 + m] = -1024.0f * s;

  _Float16* dst =
      (_Float16*)(tbase + 256 + (size_t)kt * 3072) + (quad * 16 + m) * 8;
  *(half8*)(dst) = hu;          // f=0 bh_u
  *(half8*)(dst + 512) = hs;    // f=1 bh_s
  *(half8*)(dst + 1024) = l8;   // f=2 bl'
}

// Block = 256 thr = 4 waves = 2 query-groups (64 q each) x 2 K-halves.
__global__ __launch_bounds__(BLOCK, 2) void vq_mfma(
    const float* __restrict__ z, const float4* __restrict__ cb4,
    const char* __restrict__ cbf, float4* __restrict__ out4) {
  __shared__ float rv[2][128];
  __shared__ int rk[2][128];
  __shared__ int sidx[128];

  const int tid = threadIdx.x;
  const int lane = tid & 63;
  const int wave = tid >> 6;
  const int qg = wave & 1;    // query group (64 queries)
  const int kh = wave >> 1;   // K half (32 tiles = 512 codes)
  const int m = lane & 15;
  const int quad = lane >> 4;

  // This wave's K-half tile stream; per-lane byte offsets are invariant.
  const char* tb = cbf + (size_t)(kh * 32) * TILE_BYTES;
  const int coff = lane * 4;                // csq' slot
  const int b0 = 256 + lane * 16;           // kt0 frags: +0 / +1024 / +2048
  const int b1 = 256 + 3072 + lane * 16;    // kt1 frags: +0 / +1024 / +2048

  // Prologue prefetch of tile 0 - in flight under the A-fragment build.
  float cnx = *(const float*)(tb + coff);
  half8 nhu0 = *(const half8*)(tb + b0);
  half8 nhs0 = *(const half8*)(tb + b0 + 1024);
  half8 nl0 = *(const half8*)(tb + b0 + 2048);
  half8 nhu1 = *(const half8*)(tb + b1);
  half8 nhs1 = *(const half8*)(tb + b1 + 1024);
  half8 nl1 = *(const half8*)(tb + b1 + 2048);

  // A-fragments: 4 qtiles x 2 ktiles, h + l'. A[m][k=quad*8+j].
  const int qbase = blockIdx.x * 128 + qg * 64;
  half8 ah[4][2], al[4][2];
#pragma unroll
  for (int qt = 0; qt < 4; ++qt) {
    const float* zr = z + (size_t)(qbase + qt * 16 + m) * DIM + quad * 8;
#pragma unroll
    for (int kt = 0; kt < 2; ++kt) {
      const float4 p0 = ((const float4*)(zr + kt * 32))[0];
      const float4 p1 = ((const float4*)(zr + kt * 32))[1];
      const float zf[8] = {p0.x, p0.y, p0.z, p0.w, p1.x, p1.y, p1.z, p1.w};
#pragma unroll
      for (int j = 0; j < 8; ++j) {
        const _Float16 h = (_Float16)zf[j];
        ah[qt][kt][j] = h;
        al[qt][kt][j] = (_Float16)((zf[j] - (float)h) * 2048.0f);
      }
    }
  }

  const float4v zvec = {0.f, 0.f, 0.f, 0.f};
  float best[4][4];
  int bestt[4][4];  // winning tile id (0..31), full u32 per slot
#pragma unroll
  for (int qt = 0; qt < 4; ++qt)
#pragma unroll
    for (int r = 0; r < 4; ++r) {
      best[qt][r] = -3.402823466e38f;
      bestt[qt][r] = 0;
    }

  const char* tbn = tb + TILE_BYTES;  // prefetch pointer (1 tile ahead)
#pragma unroll 2
  for (int t = 0; t < 32; ++t, tbn += TILE_BYTES) {
    // Rotate in the tile prefetched last iteration.
    const half8 hu0 = nhu0, hs0 = nhs0, l0 = nl0;
    const half8 hu1 = nhu1, hs1 = nhs1, l1 = nl1;
    const float c = cnx;

    // Prefetch tile t+1 (last iteration reads past our K-half: harmless,
    // stays inside the 256 MiB workspace, values never consumed).
    cnx = *(const float*)(tbn + coff);
    nhu0 = *(const half8*)(tbn + b0);
    nhs0 = *(const half8*)(tbn + b0 + 1024);
    nl0 = *(const half8*)(tbn + b0 + 2048);
    nhu1 = *(const half8*)(tbn + b1);
    nhs1 = *(const half8*)(tbn + b1 + 1024);
    nl1 = *(const half8*)(tbn + b1 + 2048);

    const float4v cvec = {c, c, c, c};

#pragma unroll
    for (int qt = 0; qt < 4; ++qt) {
      // Two INDEPENDENT 3-deep chains (kt0 and kt1), combined per slot.
      //   SA = csq' + al0'*bh_u0 + ah0*bl0' + ah0*bh_s0
      //   SB =    0 + al1'*bh_u1 + ah1*bl1' + ah1*bh_s1
      float4v SA = __builtin_amdgcn_mfma_f32_16x16x32_f16(al[qt][0], hu0, cvec, 0, 0, 0);
      float4v SB = __builtin_amdgcn_mfma_f32_16x16x32_f16(al[qt][1], hu1, zvec, 0, 0, 0);
      SA = __builtin_amdgcn_mfma_f32_16x16x32_f16(ah[qt][0], l0, SA, 0, 0, 0);
      SB = __builtin_amdgcn_mfma_f32_16x16x32_f16(ah[qt][1], l1, SB, 0, 0, 0);
      SA = __builtin_amdgcn_mfma_f32_16x16x32_f16(ah[qt][0], hs0, SA, 0, 0, 0);
      SB = __builtin_amdgcn_mfma_f32_16x16x32_f16(ah[qt][1], hs1, SB, 0, 0, 0);
#pragma unroll
      for (int r = 0; r < 4; ++r) {
        const float v = SA[r] + SB[r];
        // 4 inst: v_add / v_cmp_gt / v_max_f32 / v_cndmask (t in SGPR).
        // t ascending per lane + strict > keeps lowest-k maximum.
        const bool gt = v > best[qt][r];
        best[qt][r] = fmaxf(v, best[qt][r]);
        bestt[qt][r] = gt ? t : bestt[qt][r];
      }
    }
  }

  // Cross-lane argmax over the 16 cols (m) in each quad; ties -> lower k.
  const int kbase = kh * 512 + m;
#pragma unroll
  for (int qt = 0; qt < 4; ++qt)
#pragma unroll
    for (int r = 0; r < 4; ++r) {
      float b = best[qt][r];
      int bk = kbase + bestt[qt][r] * 16;
#pragma unroll
      for (int s = 1; s < 16; s <<= 1) {
        const float ob = __shfl_xor(b, s);
        const int obk = __shfl_xor(bk, s);
        if (ob > b || (ob == b && obk < bk)) { b = ob; bk = obk; }
      }
      if (m == 0) {
        const int qb = qg * 64 + qt * 16 + quad * 4 + r;  // row = quad*4+r
        rv[kh][qb] = b;
        rk[kh][qb] = bk;
      }
    }
  __syncthreads();

  // Combine K-halves (strict >: ties -> half 0 = lower k).
  if (tid < 128) {
    const float v0 = rv[0][tid], v1 = rv[1][tid];
    sidx[tid] = (v1 > v0) ? rk[1][tid] : rk[0][tid];
  }
  __syncthreads();

  // Gather winning fp32 codebook rows; coalesced float4 writes.
  const size_t obase = (size_t)blockIdx.x * 128 * (DIM / 4);
#pragma unroll
  for (int f0 = 0; f0 < 128 * (DIM / 4); f0 += BLOCK) {
    const int f = f0 + tid;
    const int q = f >> 4, e = f & 15;
    out4[obase + f] = cb4[(size_t)sidx[q] * (DIM / 4) + e];
  }
}

extern "C" void kernel_launch(void* const* d_in, const int* in_sizes, int n_in,
                              void* d_out, int out_size, void* d_ws, size_t ws_size,
                              hipStream_t stream) {
  const float* z = (const float*)d_in[0];
  const float* cb = (const float*)d_in[1];
  char* cbf = (char*)d_ws;  // 64 tiles x 6400 B = 400 KB

  const int nq = in_sizes[0] / DIM;  // 65536
  prep_kernel<<<(KCODES * 8) / BLOCK, BLOCK, 0, stream>>>(cb, cbf);
  vq_mfma<<<nq / 128, BLOCK, 0, stream>>>(z, (const float4*)cb, cbf,
                                          (float4*)d_out);
}